// Round 2
// baseline (1180.195 us; speedup 1.0000x reference)
//
#include <hip/hip_runtime.h>

// NonLinearSAGE: only nodes i % 3 == 0 reach the output, so we aggregate
// only edges with dst % 3 == 0 into a compact agg[dst/3] array (1M floats).
//
// Dtypes per the reference (fp32 problem; edge_index int64 -> int32 on device):
//   0: x        [3,000,000] float
//   1: edge_idx [96,000,000] int32  (first 48M = src, next 48M = dst)
//   2: W_l [1] f32   3: W_r [1] f32
//   4: W1 [2] f32    5: b1 [2] f32
//   6: W2 [2] f32    7: b2 [1] f32
// d_out: [1,000,000] float

static constexpr int kNodes = 3000000;
static constexpr int kEdges = 48000000;
static constexpr int kOut   = 1000000;   // kNodes / 3

__global__ __launch_bounds__(256) void edge_scatter(
    const int* __restrict__ ei,
    const float* __restrict__ x,
    float* __restrict__ agg)
{
    const int tid = blockIdx.x * blockDim.x + threadIdx.x;
    const int e = tid * 4;                 // kEdges divisible by 4
    if (e >= kEdges) return;

    const int4 s4 = *reinterpret_cast<const int4*>(ei + e);           // src
    const int4 d4 = *reinterpret_cast<const int4*>(ei + kEdges + e);  // dst

    const int ss[4] = {s4.x, s4.y, s4.z, s4.w};
    const int dd[4] = {d4.x, d4.y, d4.z, d4.w};

#pragma unroll
    for (int k = 0; k < 4; ++k) {
        const unsigned d = (unsigned)dd[k];
        const unsigned q = d / 3u;         // compiler emits magic-multiply
        if (q * 3u == d) {                 // dst % 3 == 0
            atomicAdd(agg + q, x[ss[k]]);
        }
    }
}

__global__ __launch_bounds__(256) void finalize(
    const float* __restrict__ agg,
    const float* __restrict__ x,
    const float* __restrict__ Wl,
    const float* __restrict__ Wr,
    const float* __restrict__ W1,
    const float* __restrict__ b1,
    const float* __restrict__ W2,
    const float* __restrict__ b2,
    float* __restrict__ out)
{
    const int j = blockIdx.x * blockDim.x + threadIdx.x;
    if (j >= kOut) return;

    const float wl  = Wl[0];
    const float wr  = Wr[0];
    const float w10 = W1[0];
    const float w11 = W1[1];
    const float bb0 = b1[0];
    const float bb1 = b1[1];
    const float w20 = W2[0];
    const float w21 = W2[1];
    const float bb2 = b2[0];

    const float h = agg[j] * wl + x[3 * j] * wr;
    const float t0 = fmaxf(h * w10 + bb0, 0.0f);
    const float t1 = fmaxf(h * w11 + bb1, 0.0f);
    out[j] = t0 * w20 + t1 * w21 + bb2;
}

extern "C" void kernel_launch(void* const* d_in, const int* in_sizes, int n_in,
                              void* d_out, int out_size, void* d_ws, size_t ws_size,
                              hipStream_t stream)
{
    const float* x  = (const float*)d_in[0];
    const int*   ei = (const int*)d_in[1];
    const float* Wl = (const float*)d_in[2];
    const float* Wr = (const float*)d_in[3];
    const float* W1 = (const float*)d_in[4];
    const float* b1 = (const float*)d_in[5];
    const float* W2 = (const float*)d_in[6];
    const float* b2 = (const float*)d_in[7];
    float* out = (float*)d_out;

    float* agg = (float*)d_ws;  // kOut floats = 4 MB, poisoned each call -> zero it

    hipMemsetAsync(agg, 0, kOut * sizeof(float), stream);

    const int nThreads = kEdges / 4;                    // 12M threads, 4 edges each
    edge_scatter<<<nThreads / 256, 256, 0, stream>>>(ei, x, agg);

    finalize<<<(kOut + 255) / 256, 256, 0, stream>>>(agg, x, Wl, Wr, W1, b1, W2, b2, out);
}